// Round 1
// baseline (278.465 us; speedup 1.0000x reference)
//
#include <hip/hip_runtime.h>
#include <hip/hip_bf16.h>
#include <stdint.h>

// CRF nllh = sum_b (logZ_b - score_b).
// logZ via chunked parallel scan in probability domain:
//   alpha_t = alpha_{t-1} * Q_t,  Q_t[i][j] = exp(trans[i][j]/w_{t-1} + em_t[j])
// Chunk c computes X_c = (Q_{t0}...Q_{t1-1})^T via bf16 MFMA (X <- Q^T X),
// with scalar rescale every 8 steps (log2 offset tracked). Combine kernel
// applies alpha0 through the 16 chunk matrices per batch.

#define T_DIM 2048
#define B_DIM 256
#define M_DIM 32
#define CHUNKS 16
#define CLEN 128

typedef __attribute__((ext_vector_type(8))) short short8;
typedef __attribute__((ext_vector_type(4))) float f32x4;

__device__ __forceinline__ int pack_bf16(float lo, float hi) {
  union { float f; uint32_t u; } a, b;
  a.f = lo; b.f = hi;
  // bytes [lo.b2, lo.b3, hi.b2, hi.b3] -> (bf16(lo) | bf16(hi)<<16), trunc rounding
  return (int)__builtin_amdgcn_perm(b.u, a.u, 0x07060302u);
}

__global__ void zero_out(float* o) { *o = 0.f; }

// ---------------- gold-path score ----------------
__global__ __launch_bounds__(256) void score_kernel(
    const float* __restrict__ em, const int* __restrict__ tags,
    const float* __restrict__ wt, const int* __restrict__ mask,
    const float* __restrict__ trans, const float* __restrict__ startt,
    const float* __restrict__ endt, float* __restrict__ out)
{
  __shared__ float tl[M_DIM * M_DIM];
  int tid = threadIdx.x;
#pragma unroll
  for (int k = 0; k < 4; ++k) tl[tid + 256 * k] = trans[tid + 256 * k];
  __syncthreads();

  int n = blockIdx.x * 256 + tid;  // n = t*B + b
  int t = n >> 8;
  int mk = mask[n];
  int tg = mk ? tags[n] : 1;
  float mf = (float)mk;
  float c = em[(size_t)n * 32 + tg] * mf;
  if (t == 0) c += startt[tg];
  if (t > 0) {
    int mkp = mask[n - B_DIM];
    int tgp = mkp ? tags[n - B_DIM] : 1;
    float w = wt[n - B_DIM];
    c += tl[tgp * 32 + tg] * mf / w;
  }
  int mkn = (t + 1 < T_DIM) ? mask[n + B_DIM] : 0;
  if (mk && !mkn) c += endt[tg];

#pragma unroll
  for (int off = 32; off; off >>= 1) c += __shfl_down(c, off);
  __shared__ float red[4];
  if ((tid & 63) == 0) red[tid >> 6] = c;
  __syncthreads();
  if (tid == 0) atomicAdd(out, -(red[0] + red[1] + red[2] + red[3]));
}

// ---------------- chunk matrix products (MFMA) ----------------
__global__ __launch_bounds__(64, 4) void chunk_kernel(
    const float* __restrict__ em, const float* __restrict__ wt,
    const int* __restrict__ mask, const float* __restrict__ trans,
    float* __restrict__ mats, float* __restrict__ offs)
{
  const float INV_LN2 = 1.44269504088896340736f;
  int lane = threadIdx.x;
  int q = lane >> 4, m = lane & 15;
  int bx = blockIdx.x;
  int b = bx & (B_DIM - 1);
  int c = bx >> 8;
  int t0 = 1 + c * CLEN;
  int t1 = t0 + CLEN; if (t1 > T_DIM) t1 = T_DIM;

  // constant A-side transitions: t2v[I*8+j] = trans[(q*8+j)][m+16I] / ln2
  float t2v[16];
#pragma unroll
  for (int I = 0; I < 2; ++I)
#pragma unroll
    for (int j = 0; j < 8; ++j)
      t2v[I * 8 + j] = trans[(q * 8 + j) * 32 + m + 16 * I] * INV_LN2;

  // X = identity; D/C layout: tile(I,J): row=16I+4q+p, col=16J+m
  f32x4 X[2][2];
#pragma unroll
  for (int I = 0; I < 2; ++I)
#pragma unroll
    for (int J = 0; J < 2; ++J)
#pragma unroll
      for (int p = 0; p < 4; ++p)
        X[I][J][p] = (I == J && (4 * q + p) == m) ? 1.f : 0.f;

  float off2 = 0.f;
  const int idxA = (((2 * q) & 3) * 16 + m) * 4;      // src lane*4 for B ints 0,1
  const int idxB = (((2 * q + 1) & 3) * 16 + m) * 4;  // src lane*4 for B ints 2,3
  const bool lowhalf = (lane < 32);                    // tile I = q>>1 select

  for (int t = t0; t < t1; ++t) {
    int mk = mask[t * B_DIM + b];
    if (mk) {
      float r = __builtin_amdgcn_rcpf(wt[(t - 1) * B_DIM + b]);
      const float* emrow = em + ((size_t)(t * B_DIM + b)) * 32;
      float ea = emrow[m] * INV_LN2;
      float eb = emrow[m + 16] * INV_LN2;

      // Q^T A-fragments: A_I[m][k=8q+j] = Q[k][m+16I] = exp2(t2*r + em2)
      float qv[16];
#pragma unroll
      for (int j = 0; j < 8; ++j) {
        qv[j]     = __builtin_amdgcn_exp2f(fmaf(t2v[j],     r, ea));
        qv[8 + j] = __builtin_amdgcn_exp2f(fmaf(t2v[8 + j], r, eb));
      }
      union { int i[4]; short8 s; } af[2];
#pragma unroll
      for (int I = 0; I < 2; ++I)
#pragma unroll
        for (int j2 = 0; j2 < 4; ++j2)
          af[I].i[j2] = pack_bf16(qv[I * 8 + 2 * j2], qv[I * 8 + 2 * j2 + 1]);

      // pack running X to bf16 pairs (rows 4q+{0,1}, 4q+{2,3})
      int xpk[2][2][2];
#pragma unroll
      for (int I = 0; I < 2; ++I)
#pragma unroll
        for (int J = 0; J < 2; ++J) {
          xpk[I][J][0] = pack_bf16(X[I][J][0], X[I][J][1]);
          xpk[I][J][1] = pack_bf16(X[I][J][2], X[I][J][3]);
        }

      // D-layout -> B-operand layout: B_J int u holds rows 8q+2u{,+1}, col 16J+m
      union { int i[4]; short8 s; } bf[2];
#pragma unroll
      for (int J = 0; J < 2; ++J) {
        int v00 = __builtin_amdgcn_ds_bpermute(idxA, xpk[0][J][0]);
        int v01 = __builtin_amdgcn_ds_bpermute(idxA, xpk[1][J][0]);
        int v10 = __builtin_amdgcn_ds_bpermute(idxA, xpk[0][J][1]);
        int v11 = __builtin_amdgcn_ds_bpermute(idxA, xpk[1][J][1]);
        int v20 = __builtin_amdgcn_ds_bpermute(idxB, xpk[0][J][0]);
        int v21 = __builtin_amdgcn_ds_bpermute(idxB, xpk[1][J][0]);
        int v30 = __builtin_amdgcn_ds_bpermute(idxB, xpk[0][J][1]);
        int v31 = __builtin_amdgcn_ds_bpermute(idxB, xpk[1][J][1]);
        bf[J].i[0] = lowhalf ? v00 : v01;
        bf[J].i[1] = lowhalf ? v10 : v11;
        bf[J].i[2] = lowhalf ? v20 : v21;
        bf[J].i[3] = lowhalf ? v30 : v31;
      }

      f32x4 z = {0.f, 0.f, 0.f, 0.f};
#pragma unroll
      for (int I = 0; I < 2; ++I)
#pragma unroll
        for (int J = 0; J < 2; ++J)
          X[I][J] = __builtin_amdgcn_mfma_f32_16x16x32_bf16(af[I].s, bf[J].s, z, 0, 0, 0);
    }

    if ((t & 7) == 7) {  // rescale: keep fp32/bf16 range safe
      float mx = X[0][0][0];
#pragma unroll
      for (int I = 0; I < 2; ++I)
#pragma unroll
        for (int J = 0; J < 2; ++J)
#pragma unroll
          for (int p = 0; p < 4; ++p) mx = fmaxf(mx, X[I][J][p]);
#pragma unroll
      for (int off = 1; off < 64; off <<= 1) mx = fmaxf(mx, __shfl_xor(mx, off));
      float sc = __builtin_amdgcn_rcpf(mx);
      off2 += __builtin_amdgcn_logf(mx);  // log2
#pragma unroll
      for (int I = 0; I < 2; ++I)
#pragma unroll
        for (int J = 0; J < 2; ++J)
#pragma unroll
          for (int p = 0; p < 4; ++p) X[I][J][p] *= sc;
    }
  }

  float* mp = mats + (size_t)(c * B_DIM + b) * 1024;
#pragma unroll
  for (int I = 0; I < 2; ++I)
#pragma unroll
    for (int J = 0; J < 2; ++J)
#pragma unroll
      for (int p = 0; p < 4; ++p)
        mp[(16 * I + 4 * q + p) * 32 + 16 * J + m] = X[I][J][p];
  if (lane == 0) offs[c * B_DIM + b] = off2;
}

// ---------------- combine chunks per batch ----------------
__global__ __launch_bounds__(64) void combine_kernel(
    const float* __restrict__ em, const float* __restrict__ startt,
    const float* __restrict__ endt, const float* __restrict__ mats,
    const float* __restrict__ offs, float* __restrict__ out)
{
  const float INV_LN2 = 1.44269504088896340736f;
  const float LN2 = 0.69314718055994530942f;
  int lane = threadIdx.x;
  int j = lane & 31;  // lanes 32-63 mirror
  int b = blockIdx.x;

  float a0 = (startt[j] + em[(size_t)b * 32 + j]) * INV_LN2;  // log2 domain
  float c0 = a0;
#pragma unroll
  for (int off = 1; off < 32; off <<= 1) c0 = fmaxf(c0, __shfl_xor(c0, off));
  float av = __builtin_amdgcn_exp2f(a0 - c0);
  float acc = c0;  // accumulated log2 offset

  for (int c = 0; c < CHUNKS; ++c) {
    const float* xr = mats + (size_t)(c * B_DIM + b) * 1024 + j * 32;  // row j
    float x[32];
#pragma unroll
    for (int k = 0; k < 8; ++k) {
      float4 v = ((const float4*)xr)[k];
      x[4 * k] = v.x; x[4 * k + 1] = v.y; x[4 * k + 2] = v.z; x[4 * k + 3] = v.w;
    }
    float an = 0.f;
#pragma unroll
    for (int i = 0; i < 32; ++i) an = fmaf(x[i], __shfl(av, i), an);
    float mx = an;
#pragma unroll
    for (int off = 1; off < 32; off <<= 1) mx = fmaxf(mx, __shfl_xor(mx, off));
    av = an * __builtin_amdgcn_rcpf(mx);
    acc += __builtin_amdgcn_logf(mx) + offs[c * B_DIM + b];
  }

  float sv = av * __builtin_amdgcn_exp2f(endt[j] * INV_LN2);
#pragma unroll
  for (int off = 1; off < 32; off <<= 1) sv += __shfl_xor(sv, off);
  if (lane == 0) {
    float logZ = (acc + __builtin_amdgcn_logf(sv)) * LN2;
    atomicAdd(out, logZ);
  }
}

extern "C" void kernel_launch(void* const* d_in, const int* in_sizes, int n_in,
                              void* d_out, int out_size, void* d_ws, size_t ws_size,
                              hipStream_t stream) {
  const float* em   = (const float*)d_in[0];
  const int*   tags = (const int*)d_in[1];
  const float* wt   = (const float*)d_in[2];
  const int*   mask = (const int*)d_in[3];
  const float* tr   = (const float*)d_in[4];
  const float* stt  = (const float*)d_in[5];
  const float* ent  = (const float*)d_in[6];
  float* out = (float*)d_out;

  float* offs = (float*)d_ws;                 // CHUNKS*B floats
  float* mats = offs + CHUNKS * B_DIM;        // CHUNKS*B*1024 floats (~16.8 MB)

  zero_out<<<1, 1, 0, stream>>>(out);
  score_kernel<<<(T_DIM * B_DIM) / 256, 256, 0, stream>>>(em, tags, wt, mask, tr, stt, ent, out);
  chunk_kernel<<<CHUNKS * B_DIM, 64, 0, stream>>>(em, wt, mask, tr, mats, offs);
  combine_kernel<<<B_DIM, 64, 0, stream>>>(em, stt, ent, mats, offs, out);
}